// Round 15
// baseline (2439.957 us; speedup 1.0000x reference)
//
#include <hip/hip_runtime.h>
#include <stdint.h>

// LSTM: B=256, T=1024, I=64, H=256, O=1. fp32 in/out, bf16 MFMA internally.
//
// Round-26: same-XCD L2 communication with BOTH known failure modes closed
// and a verified fallback. Ledger: MALL path is latency-floor-bound at
// ~5300cy/step (R21/22/24/25 refuted fan-in/overlap/spill/pacing/publish-
// primitive). L2 path failures understood: R12 (plain sc0 loads) = consumer
// L1 STALENESS (poll addresses recur every 2 steps; line stays in L1 ->
// stale re-hit -> dead-latch, absmax 0.114); R13 (atomic RMW polls) = L2
// atomic-unit serialization (18k cy/step). Fix:
//   producer: global_atomic_swap_x2 (no sc1 -> executes at XCD L2;
//     R13-verified correct) into FAST region + plain agent store into a
//     SLOW mirror region (R24-verified) - dual publish, fire-and-forget.
//   consumer: poll FAST region with global_load_dwordx2 sc0 nt -
//     nt = no-allocate, poll lines never enter L1 -> every sweep reads the
//     XCD L2 (~250cy RT vs ~1-2k MALL); zero atomics.
//   fallback: if a lane fails FASTCAP fast sweeps it latches off forever
//     and uses the R24 agent poll on the slow mirror -> correctness NEVER
//     depends on nt semantics. Group-on-one-XCD verified at runtime by the
//     R13-proven XCC_ID consensus handshake (R13's fast-path engagement
//     proves round-robin puts bid%8==g%8 groups on one XCD); split groups
//     run pure R24.
// Cross-run staleness (fast region, L2): first touch per line this run is
// a poll fill (stale tag 1023/1024/HTAG != expected 1/2) followed by this
// run's swap overwrite; once swapped, MALL only ever receives THIS run's
// evicted values -> no stale tag can collide with its expected poll. Slow
// region: R24's argument unchanged. Handshake slots (fast parity0,
// gbase+0..7) are overwritten only by tag-2 swaps, causally after all
// peers' handshake reads (R13 argument).
//
// Carried from R24 (verified): E1 load-paced quiet poll (no s_sleep),
// E2 own-slice shortcut (own 32 hid written to LDS locally; own-threads
// skip polling), E3 acc-init + x-part MFMAs in the poll shadow. Structure
// (R3/R9/R11): 256 blocks = 32 groups x 8 slices; weights register-
// resident; 8B units {2xbf16 h pair, tag=step}; tag poison 0xAAAAAAAA;
// dead-latch caps => wrong-answer-not-hang.
//
// ws layout (u64 units): fast parities [0,2*UPP) | slow mirror
// [2*UPP,4*UPP) = 1MB total. fc reads slow parity0 (tag-1024, agent).

#define T_ 1024
#define I_ 64
#define H_ 256
#define NSLICE 8
#define NGROUP 32
#define MB 8      /* batches per group  */
#define HB 32     /* hidden units per block */
#define HROW 272  /* padded h_lds row (ushorts), 544 B = 34 x 16 B */

#define UNITS_PER_GROUP 1024                       /* 8B units per step */
#define UPP (NGROUP * UNITS_PER_GROUP)             /* units per parity */
#define SENT_CAP (1 << 16)   /* slow-poll dead-latch */
#define FASTCAP 24           /* fast sweeps before per-lane latch-off */
#define HTAG 0x48414E44u     /* "HAND" != live tags 1..1024, != poison */
#define HS_CAP (1 << 20)     /* handshake sweep cap: never trips */

typedef float floatx4 __attribute__((ext_vector_type(4)));
typedef __bf16 bf16x8 __attribute__((ext_vector_type(8)));
typedef unsigned short ushortx8 __attribute__((ext_vector_type(8)));
typedef unsigned int uintx4 __attribute__((ext_vector_type(4)));
typedef unsigned int uint32;
typedef unsigned long long u64;

__device__ __forceinline__ float bf2f(uint32 u16) {
  uint32 u = u16 << 16;
  return __builtin_bit_cast(float, u);
}
__device__ __forceinline__ bf16x8 packbf8(floatx4 a, floatx4 b) {
  bf16x8 r;
  r[0] = (__bf16)a[0]; r[1] = (__bf16)a[1];
  r[2] = (__bf16)a[2]; r[3] = (__bf16)a[3];
  r[4] = (__bf16)b[0]; r[5] = (__bf16)b[1];
  r[6] = (__bf16)b[2]; r[7] = (__bf16)b[3];
  return r;
}
__device__ __forceinline__ float fast_sig(float v) {
  return 1.0f / (1.0f + __expf(-v));
}
__device__ __forceinline__ float fast_tanh(float v) {
  float e = __expf(2.0f * v);
  return 1.0f - 2.0f / (e + 1.0f);
}
__device__ __forceinline__ u64 aload64(const u64* p) {
  return __hip_atomic_load(p, __ATOMIC_RELAXED, __HIP_MEMORY_SCOPE_AGENT);
}
__device__ __forceinline__ void astore64(u64* p, u64 v) {
  __hip_atomic_store(p, v, __ATOMIC_RELAXED, __HIP_MEMORY_SCOPE_AGENT);
}
// no-return 8B swap at the XCD L2 (no sc1) - R13-verified correct.
__device__ __forceinline__ void pubswap(u64* p, u64 v) {
  asm volatile("global_atomic_swap_x2 %0, %1, off" ::"v"(p), "v"(v)
               : "memory");
}
__device__ __forceinline__ int xcc_id() {
  int x;
  asm volatile("s_getreg_b32 %0, hwreg(HW_REG_XCC_ID)" : "=s"(x));
  return x & 0xf;
}
__device__ __forceinline__ bool tags4(u64 v0, u64 v1, u64 v2, u64 v3,
                                      int t) {
  return ((uint32)(v0 >> 32) == (uint32)t) &
         ((uint32)(v1 >> 32) == (uint32)t) &
         ((uint32)(v2 >> 32) == (uint32)t) &
         ((uint32)(v3 >> 32) == (uint32)t);
}

__global__ __launch_bounds__(256, 1) void lstm_main(
    const float* __restrict__ x, const float* __restrict__ W_ih,
    const float* __restrict__ W_hh, const float* __restrict__ b_ih,
    const float* __restrict__ b_hh, u64* __restrict__ units) {
  const int tid = threadIdx.x;
  const int bid = blockIdx.x;
  const int s = bid >> 5;     // slice 0..7  (bid%8 == g%8 -> group on 1 XCD)
  const int g = bid & 31;     // group 0..31
  const int w = tid >> 6;     // wave id == gate type (i,f,g,o)
  const int lane = tid & 63;
  const int ln = lane & 15;   // MFMA n / A m
  const int lk = lane >> 4;   // MFMA k-subgroup (8 elems each)

  __shared__ float xch[4][2][16][8];                     // [gate][j][n][m]
  __shared__ __align__(16) unsigned short h_lds[MB][HROW];

  const size_t gbase = (size_t)g * UNITS_PER_GROUP;

  // ---- publish my XCD id ASAP (agent -> MALL; R13-verified handshake) ----
  if (tid == 0) {
    u64 hv = (u64)(uint32)xcc_id() | ((u64)HTAG << 32);
    astore64(units + gbase + s, hv);
  }

  // zero h_lds (h_0 = 0 for t=0; also clears pad)
  {
    uint32* p = (uint32*)&h_lds[0][0];
    for (int i = tid; i < MB * HROW / 2; i += 256) p[i] = 0u;
  }

  // ---- preload weight B-fragments (bf16) + bias, once ----
  bf16x8 wf[2][10];
  float bias[2];
#pragma unroll
  for (int j = 0; j < 2; ++j) {
    const int row = w * 256 + s * HB + j * 16 + ln;
    bias[j] = b_ih[row] + b_hh[row];
#pragma unroll
    for (int kc = 0; kc < 10; ++kc) {
      const int kk = kc * 32 + lk * 8;
      const float* src = (kk < I_) ? (W_ih + (size_t)row * I_ + kk)
                                   : (W_hh + (size_t)row * H_ + (kk - I_));
      floatx4 f0 = *(const floatx4*)src;
      floatx4 f1 = *(const floatx4*)(src + 4);
      wf[j][kc] = packbf8(f0, f1);
    }
  }

  // ---- XCD consensus (R13-verified): all threads poll the 8 slots ----
  bool fast;
  {
    u64 idv[8] = {0, 0, 0, 0, 0, 0, 0, 0};
    bool hok = false;
    for (int it = 0; !hok && it < HS_CAP; ++it) {
      hok = true;
#pragma unroll
      for (int p = 0; p < 8; ++p) {
        idv[p] = aload64(units + gbase + p);
        hok &= ((uint32)(idv[p] >> 32) == HTAG);
      }
      if (!hok) __builtin_amdgcn_s_sleep(2);
    }
    fast = hok;
#pragma unroll
    for (int p = 1; p < 8; ++p) fast &= ((uint32)idv[0] == (uint32)idv[p]);
  }

  const int mb = ln & 7;                       // batch row (m>=8 duplicates)
  const float* xrow = x + ((size_t)(g * MB + mb)) * T_ * I_;
  // update-phase roles
  const int um = tid >> 5;                     // 0..7 batch
  const int uh = tid & 31;                     // 0..31 hidden local
  const int uj = uh >> 4, un = uh & 15;
  float c_reg = 0.0f;

  // E2: own-slice threads never poll (cols written locally)
  const bool ownthr = (((tid & 31) >> 2) == s);
  bool fastlane = fast;  // per-lane latch: off forever after a FASTCAP miss

  __syncthreads();

#define FASTLOAD()                                                         \
  asm volatile(                                                            \
      "global_load_dwordx2 %0, %4, off sc0 nt\n\t"                         \
      "global_load_dwordx2 %1, %4, off offset:8 sc0 nt\n\t"                \
      "global_load_dwordx2 %2, %4, off offset:16 sc0 nt\n\t"               \
      "global_load_dwordx2 %3, %4, off offset:24 sc0 nt\n\t"               \
      "s_waitcnt vmcnt(0)"                                                 \
      : "=&v"(v0), "=&v"(v1), "=&v"(v2), "=&v"(v3)                         \
      : "v"(fup)                                                           \
      : "memory");

#pragma unroll 1
  for (int t = 0; t < T_; ++t) {
    // x loads issued first so they overlap the poll
    floatx4 xf0, xf1, xf2, xf3;
    {
      const float* src = xrow + t * I_ + lk * 8;
      xf0 = *(const floatx4*)(src);
      xf1 = *(const floatx4*)(src + 4);
      xf2 = *(const floatx4*)(src + 32);
      xf3 = *(const floatx4*)(src + 36);
    }

    const u64* fup = units + (size_t)(t & 1) * UPP + gbase + tid * 4;
    const u64* sup = fup + 2 * UPP;  // slow mirror
    u64 v0 = 0, v1 = 0, v2 = 0, v3 = 0;
    const bool polling = (t > 0) && !ownthr;
    const bool pre = polling && !fastlane;  // slow lanes pre-issue (R24 E3)
    if (pre) {
      v0 = aload64(sup + 0);
      v1 = aload64(sup + 1);
      v2 = aload64(sup + 2);
      v3 = aload64(sup + 3);
    }

    // ---- E3: acc init + x-part MFMAs (no h dependency, poll shadow) ----
    bf16x8 a0 = packbf8(xf0, xf1);
    bf16x8 a1 = packbf8(xf2, xf3);
    floatx4 acc[2];
    acc[0] = (floatx4){bias[0], bias[0], bias[0], bias[0]};
    acc[1] = (floatx4){bias[1], bias[1], bias[1], bias[1]};
    acc[0] = __builtin_amdgcn_mfma_f32_16x16x32_bf16(a0, wf[0][0], acc[0],
                                                     0, 0, 0);
    acc[1] = __builtin_amdgcn_mfma_f32_16x16x32_bf16(a0, wf[1][0], acc[1],
                                                     0, 0, 0);
    acc[0] = __builtin_amdgcn_mfma_f32_16x16x32_bf16(a1, wf[0][1], acc[0],
                                                     0, 0, 0);
    acc[1] = __builtin_amdgcn_mfma_f32_16x16x32_bf16(a1, wf[1][1], acc[1],
                                                     0, 0, 0);

    if (t > 0) {
      bool got = false;
      // ---- fast phase: nt polls of the XCD L2 (no L1 allocate) ----
      {
        bool fok = !(polling && fastlane);
        if (polling && fastlane) {
          FASTLOAD();
          fok = tags4(v0, v1, v2, v3, t);
        }
        int fit = 0;
        while (!__all(fok) && ++fit < FASTCAP) {
          if (!fok) {
            FASTLOAD();
            fok = tags4(v0, v1, v2, v3, t);
          }
        }
        if (polling && fastlane) {
          if (fok) got = true;
          else fastlane = false;  // latch off: nt not L2-fresh here
        }
      }
      // ---- slow phase: R24 agent poll on the slow mirror ----
      {
        bool sok = !polling || got;
        if (polling && !got && !pre) {
          v0 = aload64(sup + 0);
          v1 = aload64(sup + 1);
          v2 = aload64(sup + 2);
          v3 = aload64(sup + 3);
        }
        if (polling && !got) sok = tags4(v0, v1, v2, v3, t);
        int it = 0;
        while (!__all(sok) && ++it < SENT_CAP) {
          if (!sok) {
            v0 = aload64(sup + 0);
            v1 = aload64(sup + 1);
            v2 = aload64(sup + 2);
            v3 = aload64(sup + 3);
            sok = tags4(v0, v1, v2, v3, t);
          }
        }
      }
      if (polling) {
        uintx4 d;
        d[0] = (uint32)v0; d[1] = (uint32)v1;
        d[2] = (uint32)v2; d[3] = (uint32)v3;
        uint32* dst = (uint32*)&h_lds[tid >> 5][0] + (tid & 31) * 4;
        *(uintx4*)dst = d;  // 16B aligned
      }
    }
    __syncthreads();  // S1: h_lds ready (capture + own-local from t-1)

    // ---- h-part MFMAs: kc 2..9 from h_lds ----
    const unsigned short* hrow = &h_lds[mb][0];
#pragma unroll
    for (int kc = 2; kc < 10; ++kc) {
      bf16x8 a = __builtin_bit_cast(
          bf16x8, *(const ushortx8*)(hrow + (kc - 2) * 32 + lk * 8));
      acc[0] = __builtin_amdgcn_mfma_f32_16x16x32_bf16(a, wf[0][kc], acc[0],
                                                       0, 0, 0);
      acc[1] = __builtin_amdgcn_mfma_f32_16x16x32_bf16(a, wf[1][kc], acc[1],
                                                       0, 0, 0);
    }

    // ---- nonlinearity (wave-uniform branch) + LDS exchange ----
#pragma unroll
    for (int j = 0; j < 2; ++j) {
      floatx4 v = acc[j];
      if (w == 2) {
        v[0] = fast_tanh(v[0]); v[1] = fast_tanh(v[1]);
        v[2] = fast_tanh(v[2]); v[3] = fast_tanh(v[3]);
      } else {
        v[0] = fast_sig(v[0]); v[1] = fast_sig(v[1]);
        v[2] = fast_sig(v[2]); v[3] = fast_sig(v[3]);
      }
      if (lk < 2) {  // valid m rows 0..7 live in lanes 0..31, m = lk*4+reg
        *(floatx4*)&xch[w][j][ln][lk * 4] = v;
      }
    }
    __syncthreads();  // S2: gates ready

    // ---- c/h update: thread = (um, uh) ----
    float ig = xch[0][uj][un][um];
    float fg = xch[1][uj][un][um];
    float gg = xch[2][uj][un][um];
    float og = xch[3][uj][un][um];
    c_reg = fg * c_reg + ig * gg;
    float hv = og * fast_tanh(c_reg);

    // pair-pack via shfl; dual publish: fast L2 swap + slow agent store;
    // E2: local LDS write for own slice.
    unsigned short hb = __builtin_bit_cast(unsigned short, (__bf16)hv);
    int pv = __shfl_xor((int)hb, 1);
    if ((uh & 1) == 0) {
      uint32 dword = (uint32)hb | ((uint32)(unsigned short)pv << 16);
      u64 val = (u64)dword | ((u64)(uint32)(t + 1) << 32);
      u64* fdst = units + (size_t)((t + 1) & 1) * UPP + gbase +
                  (um * 128 + s * 16 + (uh >> 1));
      if (fast) pubswap(fdst, val);  // XCD-L2 publish (block-uniform cond)
      astore64(fdst + 2 * UPP, val); // slow mirror (MALL, R24-verified)
      *(uint32*)&h_lds[um][2 * (s * 16 + (uh >> 1))] = dword;
    }
  }
#undef FASTLOAD
}

// out[b] = dot(h_T[b], fc_w) + fc_b. Final h = tag-1024 units in SLOW
// mirror parity 0 (agent-stored, MALL-authoritative, replay-safe).
__global__ void lstm_fc(const u64* __restrict__ units,
                        const float* __restrict__ fc_w,
                        const float* __restrict__ fc_b,
                        float* __restrict__ out) {
  const int b = threadIdx.x;
  const int g = b >> 3, m = b & 7;
  const u64* base =
      units + 2 * (size_t)UPP + (size_t)g * UNITS_PER_GROUP + m * 128;
  float sum = fc_b[0];
#pragma unroll 8
  for (int d = 0; d < 128; ++d) {
    u64 v = aload64(base + d);
    uint32 lo = (uint32)v;
    sum += bf2f(lo & 0xffffu) * fc_w[2 * d] + bf2f(lo >> 16) * fc_w[2 * d + 1];
  }
  out[b] = sum;
}

extern "C" void kernel_launch(void* const* d_in, const int* in_sizes, int n_in,
                              void* d_out, int out_size, void* d_ws,
                              size_t ws_size, hipStream_t stream) {
  const float* x    = (const float*)d_in[0];
  const float* W_ih = (const float*)d_in[1];
  const float* W_hh = (const float*)d_in[2];
  const float* b_ih = (const float*)d_in[3];
  const float* b_hh = (const float*)d_in[4];
  const float* fc_w = (const float*)d_in[5];
  const float* fc_b = (const float*)d_in[6];
  float* out = (float*)d_out;

  u64* units = (u64*)d_ws;  // fast 2 parities + slow mirror 2 = 1MB ws
  // tag poison 0xAAAAAAAA != any live tag (1..1024) => no init needed.

  lstm_main<<<dim3(NGROUP * NSLICE), dim3(256), 0, stream>>>(
      x, W_ih, W_hh, b_ih, b_hh, units);
  lstm_fc<<<dim3(1), dim3(256), 0, stream>>>(units, fc_w, fc_b, out);
}